// Round 6
// baseline (361.976 us; speedup 1.0000x reference)
//
#include <hip/hip_runtime.h>
#include <math.h>

#define NN 50000
#define NE 800000
#define FD 128      // IN == HC == 128
#define NB 64
#define NBUK 196            // ceil(NN/256) buckets of 256 dst nodes
#define CHK 3125            // NE / 256 blocks
#define CAP 6144            // LDS staging capacity per bucket (mean 4082, std ~64)

typedef __attribute__((ext_vector_type(8))) short short8v;
typedef __attribute__((ext_vector_type(4))) float f32x4;

// ---------------- init: zero bucket counts + pooled accumulators ----------------
__global__ void k_init(int* __restrict__ bcnt, float* __restrict__ pooled) {
  int i = blockIdx.x * blockDim.x + threadIdx.x;
  if (i < NBUK) bcnt[i] = 0;
  if (i < NB * FD) pooled[i] = 0.f;
}

// ---------------- bucket histogram (dst >> 8) ----------------
__global__ __launch_bounds__(256) void k_bhist(const int* __restrict__ dst,
                                               int* __restrict__ bcnt) {
  __shared__ int bh[NBUK];
  int t = threadIdx.x;
  for (int i = t; i < NBUK; i += 256) bh[i] = 0;
  __syncthreads();
  int e0 = blockIdx.x * CHK, e1 = e0 + CHK;
  if (e1 > NE) e1 = NE;
  for (int e = e0 + t; e < e1; e += 256) atomicAdd(&bh[dst[e] >> 8], 1);
  __syncthreads();
  for (int i = t; i < NBUK; i += 256) if (bh[i]) atomicAdd(&bcnt[i], bh[i]);
}

// ---------------- scan of 196 bucket counts ----------------
__global__ __launch_bounds__(256) void k_bscan(const int* __restrict__ bcnt,
                                               int* __restrict__ bbase,
                                               int* __restrict__ bcur) {
  __shared__ int wsum[4];
  int t = threadIdx.x;
  int v = (t < NBUK) ? bcnt[t] : 0;
  int lane = t & 63, wv = t >> 6;
  int s = v;
  #pragma unroll
  for (int off = 1; off < 64; off <<= 1) {
    int y = __shfl_up(s, off, 64);
    if (lane >= off) s += y;
  }
  if (lane == 63) wsum[wv] = s;
  __syncthreads();
  if (t == 0) {
    int r = 0;
    #pragma unroll
    for (int i = 0; i < 4; ++i) { int x = wsum[i]; wsum[i] = r; r += x; }
  }
  __syncthreads();
  int excl = s - v + wsum[wv];
  if (t < NBUK) { bbase[t] = excl; bcur[t] = excl; }
  if (t == NBUK - 1) bbase[NBUK] = excl + v;
}

// ---------------- bucketed scatter: edges -> bucket-ordered packed list ----------------
// pkt = (src << 8) | (dst & 255); src < 50000 < 2^16 so pkt fits 24 bits.
__global__ __launch_bounds__(256) void k_bscatter(const int* __restrict__ src,
    const int* __restrict__ dst, int* __restrict__ bcur, int* __restrict__ tmpv) {
  __shared__ int bh[NBUK];
  __shared__ int bb[NBUK];
  __shared__ int brun[NBUK];
  int t = threadIdx.x;
  int e0 = blockIdx.x * CHK, e1 = e0 + CHK;
  if (e1 > NE) e1 = NE;
  for (int i = t; i < NBUK; i += 256) { bh[i] = 0; brun[i] = 0; }
  __syncthreads();
  for (int e = e0 + t; e < e1; e += 256) atomicAdd(&bh[dst[e] >> 8], 1);
  __syncthreads();
  for (int i = t; i < NBUK; i += 256)
    bb[i] = bh[i] ? atomicAdd(&bcur[i], bh[i]) : 0;
  __syncthreads();
  for (int e = e0 + t; e < e1; e += 256) {
    int d = dst[e];
    int bk = d >> 8;
    int p = bb[bk] + atomicAdd(&brun[bk], 1);
    tmpv[p] = (src[e] << 8) | (d & 255);
  }
}

// ---------------- per-bucket CSR finalize: offs + sorted ssrc, all in LDS ----------------
__global__ __launch_bounds__(256) void k_bcsr(const int* __restrict__ tmpv,
    const int* __restrict__ bbase, int* __restrict__ offs, int* __restrict__ ssrc) {
  __shared__ int sdeg[256];
  __shared__ int scur[256];
  __shared__ int wsum[4];
  __shared__ int lsrc[CAP];
  int b = blockIdx.x, t = threadIdx.x;
  int es = bbase[b], ee = bbase[b + 1];
  int cnt = ee - es;
  sdeg[t] = 0;
  __syncthreads();
  for (int i = t; i < cnt; i += 256) atomicAdd(&sdeg[tmpv[es + i] & 255], 1);
  __syncthreads();
  int v = sdeg[t];
  int lane = t & 63, wv = t >> 6;
  int s = v;
  #pragma unroll
  for (int off = 1; off < 64; off <<= 1) {
    int y = __shfl_up(s, off, 64);
    if (lane >= off) s += y;
  }
  if (lane == 63) wsum[wv] = s;
  __syncthreads();
  if (t == 0) {
    int r = 0;
    #pragma unroll
    for (int i = 0; i < 4; ++i) { int x = wsum[i]; wsum[i] = r; r += x; }
  }
  __syncthreads();
  int excl = s - v + wsum[wv];
  scur[t] = excl;
  int node = b * 256 + t;
  if (node < NN) offs[node] = es + excl;
  if (b == NBUK - 1 && t == 0) offs[NN] = NE;
  __syncthreads();
  if (cnt <= CAP) {
    for (int i = t; i < cnt; i += 256) {
      int pkt = tmpv[es + i];
      int p = atomicAdd(&scur[pkt & 255], 1);
      lsrc[p] = pkt >> 8;
    }
    __syncthreads();
    for (int i = t; i < cnt; i += 256) ssrc[es + i] = lsrc[i];
  } else {  // statistically impossible fallback, kept for safety
    for (int i = t; i < cnt; i += 256) {
      int pkt = tmpv[es + i];
      int p = atomicAdd(&scur[pkt & 255], 1);
      ssrc[es + p] = pkt >> 8;
    }
  }
}

// ---------------- bf16 helpers ----------------
__device__ __forceinline__ unsigned short f2bf(float f) {
  unsigned u = __float_as_uint(f);
  u += 0x7fffu + ((u >> 16) & 1);          // RNE
  return (unsigned short)(u >> 16);
}
__device__ __forceinline__ float bfh2f(unsigned short h) {
  return __uint_as_float(((unsigned)h) << 16);
}

// ---------------- pre-split the 5 weight matrices into bf16 hi/lo images ------------
// Plain row-major [w][row][k] bf16 — B-fragments are loaded straight from these.
__global__ __launch_bounds__(256) void k_wprep(const float* __restrict__ W0,
    const float* __restrict__ W1, const float* __restrict__ W2,
    const float* __restrict__ W3, const float* __restrict__ W4,
    unsigned short* __restrict__ wh, unsigned short* __restrict__ wl) {
  int id = blockIdx.x * 256 + threadIdx.x;
  if (id >= 5 * 2048) return;
  int w = id >> 11, rem = id & 2047;
  int row = rem >> 4, slot = rem & 15;
  const float* Wp = (w == 0) ? W0 : (w == 1) ? W1 : (w == 2) ? W2 : (w == 3) ? W3 : W4;
  const float* sp = &Wp[row * 128 + slot * 8];
  size_t dst = (size_t)w * 16384 + row * 128 + slot * 8;
  short8v hi, lo;
  #pragma unroll
  for (int j = 0; j < 8; ++j) {
    float f = sp[j];
    unsigned short h = f2bf(f);
    hi[j] = (short)h;
    lo[j] = (short)f2bf(f - bfh2f(h));
  }
  *(short8v*)&wh[dst] = hi;
  *(short8v*)&wl[dst] = lo;
}

// ---------------- MFMA linear, no LDS, no barriers --------------------------------
// One wave owns a 32(M) x 64(N) output tile. A fp32 rows read directly from global
// and hi/lo-split in registers; W bf16 hi/lo fragments read directly from the
// prepped image (L1/L2-resident, 64 KB/matrix). 3 MFMA per K-slice (hi*hi + hi*lo
// + lo*hi), fp32 accumulate. out_bf (packed bf16) and/or out_f may be null.
__global__ __launch_bounds__(256) void k_lin(const float* __restrict__ in,
    const unsigned short* __restrict__ wh_img, const unsigned short* __restrict__ wl_img,
    int widx, const float* __restrict__ bias,
    unsigned short* __restrict__ out_bf, float* __restrict__ out_f, int nrows) {
  const int lane = threadIdx.x & 63;
  const int wv = threadIdx.x >> 6;
  const int wid = blockIdx.x * 4 + wv;
  const int rtile = wid >> 1, nh = wid & 1;
  const int m0 = rtile * 32, n0 = nh * 64;
  if (m0 >= nrows) return;
  const int g = lane >> 4, lr = lane & 15;
  const unsigned short* wh = wh_img + (size_t)widx * 16384;
  const unsigned short* wl = wl_img + (size_t)widx * 16384;

  f32x4 acc[2][4];
  #pragma unroll
  for (int mt = 0; mt < 2; ++mt)
    #pragma unroll
    for (int nt = 0; nt < 4; ++nt)
      acc[mt][nt] = (f32x4){0.f, 0.f, 0.f, 0.f};

  int arow[2];
  #pragma unroll
  for (int mt = 0; mt < 2; ++mt) {
    int r = m0 + mt * 16 + lr;
    arow[mt] = (r < nrows) ? r : (nrows - 1);   // clamp: values harmless, stores guarded
  }

  #pragma unroll
  for (int ks = 0; ks < 4; ++ks) {
    int k0 = ks * 32 + g * 8;
    short8v ah[2], al[2];
    #pragma unroll
    for (int mt = 0; mt < 2; ++mt) {
      const float* ap = &in[(size_t)arow[mt] * 128 + k0];
      float4 a0 = *(const float4*)ap;
      float4 a1 = *(const float4*)(ap + 4);
      float f[8] = {a0.x, a0.y, a0.z, a0.w, a1.x, a1.y, a1.z, a1.w};
      #pragma unroll
      for (int j = 0; j < 8; ++j) {
        unsigned short h = f2bf(f[j]);
        ah[mt][j] = (short)h;
        al[mt][j] = (short)f2bf(f[j] - bfh2f(h));
      }
    }
    #pragma unroll
    for (int nt = 0; nt < 4; ++nt) {
      int wrow = n0 + nt * 16 + lr;
      short8v bh = *(const short8v*)&wh[wrow * 128 + k0];
      short8v bl = *(const short8v*)&wl[wrow * 128 + k0];
      #pragma unroll
      for (int mt = 0; mt < 2; ++mt) {
        acc[mt][nt] = __builtin_amdgcn_mfma_f32_16x16x32_bf16(ah[mt], bh, acc[mt][nt], 0, 0, 0);
        acc[mt][nt] = __builtin_amdgcn_mfma_f32_16x16x32_bf16(ah[mt], bl, acc[mt][nt], 0, 0, 0);
        acc[mt][nt] = __builtin_amdgcn_mfma_f32_16x16x32_bf16(al[mt], bh, acc[mt][nt], 0, 0, 0);
      }
    }
  }
  // epilogue: D row = 4*g + i, col = lr within each 16x16 tile
  #pragma unroll
  for (int nt = 0; nt < 4; ++nt) {
    float bv = bias[n0 + nt * 16 + lr];
    #pragma unroll
    for (int mt = 0; mt < 2; ++mt)
      #pragma unroll
      for (int i = 0; i < 4; ++i) {
        int r = m0 + mt * 16 + 4 * g + i;
        if (r < nrows) {
          float vv = acc[mt][nt][i] + bv;
          size_t o = (size_t)r * 128 + n0 + nt * 16 + lr;
          if (out_bf) out_bf[o] = f2bf(vv);
          if (out_f) out_f[o] = vv;
        }
      }
  }
}

__device__ __forceinline__ float lrelu(float x) { return x > 0.f ? x : 0.2f * x; }

// ---------------- GATv2: bf16 gathers, no-max softmax (|s| <= ~1.5), 8-wide MLP ----
__global__ __launch_bounds__(256) void k_gat(const unsigned short* __restrict__ xl,
    const unsigned short* __restrict__ xr, const int* __restrict__ offs,
    const int* __restrict__ ssrc, const float* __restrict__ att,
    const float* __restrict__ bias, const float* __restrict__ resid,
    float* __restrict__ out) {
  int grp = threadIdx.x >> 5;
  int lane = threadIdx.x & 31;
  int n = blockIdx.x * 8 + grp;
  if (n >= NN) return;
  float4 att4 = ((const float4*)att)[lane];
  ushort4 xu = ((const ushort4*)xr)[(size_t)n * 32 + lane];
  float4 xr4 = make_float4(bfh2f(xu.x), bfh2f(xu.y), bfh2f(xu.z), bfh2f(xu.w));
  int e0 = offs[n], e1 = offs[n + 1];
  float den = 0.f;
  float4 acc = make_float4(0.f, 0.f, 0.f, 0.f);
  int e = e0;
  for (; e + 7 < e1; e += 8) {
    ushort4 u[8];
    #pragma unroll
    for (int j = 0; j < 8; ++j) {
      int s = ssrc[e + j];
      u[j] = ((const ushort4*)xl)[(size_t)s * 32 + lane];
    }
    #pragma unroll
    for (int j = 0; j < 8; ++j) {
      float4 v = make_float4(bfh2f(u[j].x), bfh2f(u[j].y), bfh2f(u[j].z), bfh2f(u[j].w));
      float p = lrelu(v.x + xr4.x) * att4.x + lrelu(v.y + xr4.y) * att4.y +
                lrelu(v.z + xr4.z) * att4.z + lrelu(v.w + xr4.w) * att4.w;
      p += __shfl_xor(p, 1, 64); p += __shfl_xor(p, 2, 64); p += __shfl_xor(p, 4, 64);
      float w = __expf(p);
      den += w;
      acc.x += w * v.x; acc.y += w * v.y; acc.z += w * v.z; acc.w += w * v.w;
    }
  }
  for (; e < e1; ++e) {
    int s = ssrc[e];
    ushort4 u0 = ((const ushort4*)xl)[(size_t)s * 32 + lane];
    float4 v = make_float4(bfh2f(u0.x), bfh2f(u0.y), bfh2f(u0.z), bfh2f(u0.w));
    float p = lrelu(v.x + xr4.x) * att4.x + lrelu(v.y + xr4.y) * att4.y +
              lrelu(v.z + xr4.z) * att4.z + lrelu(v.w + xr4.w) * att4.w;
    p += __shfl_xor(p, 1, 64); p += __shfl_xor(p, 2, 64); p += __shfl_xor(p, 4, 64);
    float w = __expf(p);
    den += w;
    acc.x += w * v.x; acc.y += w * v.y; acc.z += w * v.z; acc.w += w * v.w;
  }
  float inv = (den > 0.f) ? 1.f / den : 0.f;
  float4 b4 = ((const float4*)bias)[lane];
  float4 r4 = ((const float4*)resid)[(size_t)n * 32 + lane];
  float4 o;
  o.x = fmaxf(acc.x * inv + b4.x, 0.f) + r4.x;
  o.y = fmaxf(acc.y * inv + b4.y, 0.f) + r4.y;
  o.z = fmaxf(acc.z * inv + b4.z, 0.f) + r4.z;
  o.w = fmaxf(acc.w * inv + b4.w, 0.f) + r4.w;
  ((float4*)out)[(size_t)n * 32 + lane] = o;
}

// ---------------- mean-pool over sorted batch, run-length-compressed atomics ----------------
__global__ __launch_bounds__(256) void k_pool(const float* __restrict__ h,
    const int* __restrict__ batch, float* __restrict__ pooled) {
  int col = threadIdx.x & 127;
  int ro = threadIdx.x >> 7;
  int n0 = blockIdx.x * 128;
  float rs = 0.f;
  int cb = -1;
  for (int i = ro; i < 128; i += 2) {
    int n = n0 + i;
    if (n >= NN) break;
    int bb = batch[n];
    if (bb != cb) {
      if (cb >= 0) atomicAdd(&pooled[cb * FD + col], rs);
      rs = 0.f; cb = bb;
    }
    rs += h[(size_t)n * FD + col];
  }
  if (cb >= 0) atomicAdd(&pooled[cb * FD + col], rs);
}

// ---------------- MLP head: one block per graph ----------------
__global__ __launch_bounds__(128) void k_mlp(const float* __restrict__ pooled,
    const int* __restrict__ batch, const float* __restrict__ domain,
    const float* __restrict__ Wg, const float* __restrict__ bg,
    const float* __restrict__ Wd, const float* __restrict__ bd,
    const float* __restrict__ Wf1, const float* __restrict__ bf1,
    const float* __restrict__ Wf2, const float* __restrict__ bf2,
    const float* __restrict__ Wf3, const float* __restrict__ bf3,
    float* __restrict__ out) {
  __shared__ float z[192];
  __shared__ float z1[128];
  __shared__ float z2[64];
  __shared__ float pm[128];
  __shared__ int cnt;
  int b = blockIdx.x, t = threadIdx.x;
  if (t == 0) {
    int lo = 0, hi = NN;
    while (lo < hi) { int mid = (lo + hi) >> 1; if (batch[mid] < b) lo = mid + 1; else hi = mid; }
    int lb = lo; lo = 0; hi = NN;
    while (lo < hi) { int mid = (lo + hi) >> 1; if (batch[mid] < b + 1) lo = mid + 1; else hi = mid; }
    cnt = lo - lb;
  }
  __syncthreads();
  float invc = 1.f / fmaxf((float)cnt, 1.f);
  pm[t] = pooled[b * FD + t] * invc;
  __syncthreads();
  {
    float a = bg[t];
    for (int k = 0; k < 128; ++k) a += pm[k] * Wg[t * 128 + k];
    z[t] = fmaxf(a, 0.f);
  }
  if (t < 64) {
    float a = bd[t];
    for (int k = 0; k < 32; ++k) a += domain[b * 32 + k] * Wd[t * 32 + k];
    z[128 + t] = fmaxf(a, 0.f);
  }
  __syncthreads();
  {
    float a = bf1[t];
    for (int k = 0; k < 192; ++k) a += z[k] * Wf1[t * 192 + k];
    z1[t] = fmaxf(a, 0.f);
  }
  __syncthreads();
  if (t < 64) {
    float a = bf2[t];
    for (int k = 0; k < 128; ++k) a += z1[k] * Wf2[t * 128 + k];
    z2[t] = fmaxf(a, 0.f);
  }
  __syncthreads();
  if (t < 64) {
    float v = z2[t] * Wf3[t];
    for (int off = 1; off < 64; off <<= 1) v += __shfl_xor(v, off, 64);
    if (t == 0) out[b] = v + bf3[0];
  }
}

extern "C" void kernel_launch(void* const* d_in, const int* in_sizes, int n_in,
                              void* d_out, int out_size, void* d_ws, size_t ws_size,
                              hipStream_t stream) {
  const float* x      = (const float*)d_in[0];
  const float* domain = (const float*)d_in[1];
  const float* Wl1 = (const float*)d_in[2];  const float* bl1 = (const float*)d_in[3];
  const float* Wr1 = (const float*)d_in[4];  const float* br1 = (const float*)d_in[5];
  const float* att1= (const float*)d_in[6];  const float* bias1=(const float*)d_in[7];
  const float* Wl2 = (const float*)d_in[8];  const float* bl2 = (const float*)d_in[9];
  const float* Wr2 = (const float*)d_in[10]; const float* br2 = (const float*)d_in[11];
  const float* att2= (const float*)d_in[12]; const float* bias2=(const float*)d_in[13];
  const float* Wres= (const float*)d_in[14]; const float* bres= (const float*)d_in[15];
  const float* Wd  = (const float*)d_in[16]; const float* bd  = (const float*)d_in[17];
  const float* Wg  = (const float*)d_in[18]; const float* bg  = (const float*)d_in[19];
  const float* Wf1 = (const float*)d_in[20]; const float* bf1 = (const float*)d_in[21];
  const float* Wf2 = (const float*)d_in[22]; const float* bf2 = (const float*)d_in[23];
  const float* Wf3 = (const float*)d_in[24]; const float* bf3 = (const float*)d_in[25];
  const int* ei    = (const int*)d_in[26];
  const int* batch = (const int*)d_in[27];
  const int* esrc = ei;
  const int* edst = ei + NE;
  float* outp = (float*)d_out;

  char* p = (char*)d_ws;
  auto carve = [&](size_t bytes) { char* r = p; p += (bytes + 255) & ~(size_t)255; return r; };
  int* bcnt     = (int*)carve((size_t)NBUK * 4);
  int* bbase    = (int*)carve((size_t)(NBUK + 1) * 4);
  int* bcur     = (int*)carve((size_t)NBUK * 4);
  int* tmpv     = (int*)carve((size_t)NE * 4);
  int* ssrc     = (int*)carve((size_t)NE * 4);
  int* offs     = (int*)carve((size_t)(NN + 1) * 4);
  unsigned short* wh = (unsigned short*)carve((size_t)5 * 16384 * 2);
  unsigned short* wl = (unsigned short*)carve((size_t)5 * 16384 * 2);
  unsigned short* xl = (unsigned short*)carve((size_t)NN * FD * 2);
  unsigned short* xr = (unsigned short*)carve((size_t)NN * FD * 2);
  float* res    = (float*)carve((size_t)NN * FD * 4);
  float* h1     = (float*)carve((size_t)NN * FD * 4);
  float* pooled = (float*)carve((size_t)NB * FD * 4);
  float* h2 = res;   // res dead after first GAT; alias

  dim3 b256(256);
  hipLaunchKernelGGL(k_init, dim3((NB * FD + 255) / 256), b256, 0, stream, bcnt, pooled);
  hipLaunchKernelGGL(k_wprep, dim3(40), b256, 0, stream, Wl1, Wr1, Wres, Wl2, Wr2, wh, wl);
  hipLaunchKernelGGL(k_bhist, dim3(256), b256, 0, stream, edst, bcnt);
  hipLaunchKernelGGL(k_bscan, dim3(1), b256, 0, stream, bcnt, bbase, bcur);
  hipLaunchKernelGGL(k_bscatter, dim3(256), b256, 0, stream, esrc, edst, bcur, tmpv);
  hipLaunchKernelGGL(k_bcsr, dim3(NBUK), b256, 0, stream, tmpv, bbase, offs, ssrc);

  // wave-tiles: ceil(NN/32) row-tiles x 2 col-halves, 4 waves per block
  int nwt = ((NN + 31) / 32) * 2;
  dim3 ling((nwt + 3) / 4);
  hipLaunchKernelGGL(k_lin, ling, b256, 0, stream, x, wh, wl, 0, bl1, xl, (float*)nullptr, NN);
  hipLaunchKernelGGL(k_lin, ling, b256, 0, stream, x, wh, wl, 1, br1, xr, (float*)nullptr, NN);
  hipLaunchKernelGGL(k_lin, ling, b256, 0, stream, x, wh, wl, 2, bres, (unsigned short*)nullptr, res, NN);
  hipLaunchKernelGGL(k_gat, dim3((NN + 7) / 8), b256, 0, stream, xl, xr, offs, ssrc, att1, bias1, res, h1);
  hipLaunchKernelGGL(k_lin, ling, b256, 0, stream, h1, wh, wl, 3, bl2, xl, (float*)nullptr, NN);
  hipLaunchKernelGGL(k_lin, ling, b256, 0, stream, h1, wh, wl, 4, br2, xr, (float*)nullptr, NN);
  hipLaunchKernelGGL(k_gat, dim3((NN + 7) / 8), b256, 0, stream, xl, xr, offs, ssrc, att2, bias2, h1, h2);
  hipLaunchKernelGGL(k_pool, dim3((NN + 127) / 128), b256, 0, stream, h2, batch, pooled);
  hipLaunchKernelGGL(k_mlp, dim3(NB), dim3(128), 0, stream, pooled, batch, domain,
                     Wg, bg, Wd, bd, Wf1, bf1, Wf2, bf2, Wf3, bf3, outp);
}

// Round 7
// 255.468 us; speedup vs baseline: 1.4169x; 1.4169x over previous
//
#include <hip/hip_runtime.h>
#include <math.h>

#define NN 50000
#define NE 800000
#define FD 128      // IN == HC == 128
#define NB 64
#define NBUK 196            // ceil(NN/256) buckets of 256 dst nodes
#define CHK 3125            // NE / 256 blocks
#define CAP 6144            // LDS staging capacity per bucket (mean 4082, std ~64)
#define NBLK 782            // ceil(NN/64) row-tiles for the linears

typedef __attribute__((ext_vector_type(8))) short short8v;
typedef __attribute__((ext_vector_type(4))) float f32x4;

// ---------------- init: zero bucket counts + pooled accumulators ----------------
__global__ void k_init(int* __restrict__ bcnt, float* __restrict__ pooled) {
  int i = blockIdx.x * blockDim.x + threadIdx.x;
  if (i < NBUK) bcnt[i] = 0;
  if (i < NB * FD) pooled[i] = 0.f;
}

// ---------------- bucket histogram (dst >> 8) ----------------
__global__ __launch_bounds__(256) void k_bhist(const int* __restrict__ dst,
                                               int* __restrict__ bcnt) {
  __shared__ int bh[NBUK];
  int t = threadIdx.x;
  for (int i = t; i < NBUK; i += 256) bh[i] = 0;
  __syncthreads();
  int e0 = blockIdx.x * CHK, e1 = e0 + CHK;
  if (e1 > NE) e1 = NE;
  for (int e = e0 + t; e < e1; e += 256) atomicAdd(&bh[dst[e] >> 8], 1);
  __syncthreads();
  for (int i = t; i < NBUK; i += 256) if (bh[i]) atomicAdd(&bcnt[i], bh[i]);
}

// ---------------- scan of 196 bucket counts ----------------
__global__ __launch_bounds__(256) void k_bscan(const int* __restrict__ bcnt,
                                               int* __restrict__ bbase,
                                               int* __restrict__ bcur) {
  __shared__ int wsum[4];
  int t = threadIdx.x;
  int v = (t < NBUK) ? bcnt[t] : 0;
  int lane = t & 63, wv = t >> 6;
  int s = v;
  #pragma unroll
  for (int off = 1; off < 64; off <<= 1) {
    int y = __shfl_up(s, off, 64);
    if (lane >= off) s += y;
  }
  if (lane == 63) wsum[wv] = s;
  __syncthreads();
  if (t == 0) {
    int r = 0;
    #pragma unroll
    for (int i = 0; i < 4; ++i) { int x = wsum[i]; wsum[i] = r; r += x; }
  }
  __syncthreads();
  int excl = s - v + wsum[wv];
  if (t < NBUK) { bbase[t] = excl; bcur[t] = excl; }
  if (t == NBUK - 1) bbase[NBUK] = excl + v;
}

// ---------------- bucketed scatter: edges -> bucket-ordered packed list ----------------
// pkt = (src << 8) | (dst & 255); src < 50000 < 2^24 so pkt fits 32 bits.
__global__ __launch_bounds__(256) void k_bscatter(const int* __restrict__ src,
    const int* __restrict__ dst, int* __restrict__ bcur, int* __restrict__ tmpv) {
  __shared__ int bh[NBUK];
  __shared__ int bb[NBUK];
  __shared__ int brun[NBUK];
  int t = threadIdx.x;
  int e0 = blockIdx.x * CHK, e1 = e0 + CHK;
  if (e1 > NE) e1 = NE;
  for (int i = t; i < NBUK; i += 256) { bh[i] = 0; brun[i] = 0; }
  __syncthreads();
  for (int e = e0 + t; e < e1; e += 256) atomicAdd(&bh[dst[e] >> 8], 1);
  __syncthreads();
  for (int i = t; i < NBUK; i += 256)
    bb[i] = bh[i] ? atomicAdd(&bcur[i], bh[i]) : 0;
  __syncthreads();
  for (int e = e0 + t; e < e1; e += 256) {
    int d = dst[e];
    int bk = d >> 8;
    int p = bb[bk] + atomicAdd(&brun[bk], 1);
    tmpv[p] = (src[e] << 8) | (d & 255);
  }
}

// ---------------- per-bucket CSR finalize: offs + sorted ssrc, all in LDS ----------------
__global__ __launch_bounds__(256) void k_bcsr(const int* __restrict__ tmpv,
    const int* __restrict__ bbase, int* __restrict__ offs, int* __restrict__ ssrc) {
  __shared__ int sdeg[256];
  __shared__ int scur[256];
  __shared__ int wsum[4];
  __shared__ int lsrc[CAP];
  int b = blockIdx.x, t = threadIdx.x;
  int es = bbase[b], ee = bbase[b + 1];
  int cnt = ee - es;
  sdeg[t] = 0;
  __syncthreads();
  for (int i = t; i < cnt; i += 256) atomicAdd(&sdeg[tmpv[es + i] & 255], 1);
  __syncthreads();
  int v = sdeg[t];
  int lane = t & 63, wv = t >> 6;
  int s = v;
  #pragma unroll
  for (int off = 1; off < 64; off <<= 1) {
    int y = __shfl_up(s, off, 64);
    if (lane >= off) s += y;
  }
  if (lane == 63) wsum[wv] = s;
  __syncthreads();
  if (t == 0) {
    int r = 0;
    #pragma unroll
    for (int i = 0; i < 4; ++i) { int x = wsum[i]; wsum[i] = r; r += x; }
  }
  __syncthreads();
  int excl = s - v + wsum[wv];
  scur[t] = excl;
  int node = b * 256 + t;
  if (node < NN) offs[node] = es + excl;
  if (b == NBUK - 1 && t == 0) offs[NN] = NE;
  __syncthreads();
  if (cnt <= CAP) {
    for (int i = t; i < cnt; i += 256) {
      int pkt = tmpv[es + i];
      int p = atomicAdd(&scur[pkt & 255], 1);
      lsrc[p] = pkt >> 8;
    }
    __syncthreads();
    for (int i = t; i < cnt; i += 256) ssrc[es + i] = lsrc[i];
  } else {  // statistically impossible fallback, kept for safety
    for (int i = t; i < cnt; i += 256) {
      int pkt = tmpv[es + i];
      int p = atomicAdd(&scur[pkt & 255], 1);
      ssrc[es + p] = pkt >> 8;
    }
  }
}

// ---------------- bf16 helpers ----------------
__device__ __forceinline__ unsigned short f2bf(float f) {
  unsigned u = __float_as_uint(f);
  u += 0x7fffu + ((u >> 16) & 1);          // RNE
  return (unsigned short)(u >> 16);
}
__device__ __forceinline__ float bfh2f(unsigned short h) {
  return __uint_as_float(((unsigned)h) << 16);
}

// ---------------- pre-split + pre-swizzle the 5 weight matrices ----------------
// Image layout per (w, kh): [row*64 + 8*((slot&7) ^ (row&7))], ready for LDS memcpy.
__global__ __launch_bounds__(256) void k_wprep(const float* __restrict__ W0,
    const float* __restrict__ W1, const float* __restrict__ W2,
    const float* __restrict__ W3, const float* __restrict__ W4,
    unsigned short* __restrict__ wh, unsigned short* __restrict__ wl) {
  int id = blockIdx.x * 256 + threadIdx.x;
  if (id >= 5 * 2048) return;
  int w = id >> 11, rem = id & 2047;
  int row = rem >> 4, slot = rem & 15;
  const float* Wp = (w == 0) ? W0 : (w == 1) ? W1 : (w == 2) ? W2 : (w == 3) ? W3 : W4;
  const float* sp = &Wp[row * 128 + slot * 8];
  int kh = slot >> 3, s7 = slot & 7;
  int dst = ((w * 2 + kh) * 8192) + row * 64 + 8 * (s7 ^ (row & 7));
  short8v hi, lo;
  #pragma unroll
  for (int j = 0; j < 8; ++j) {
    float f = sp[j];
    unsigned short h = f2bf(f);
    hi[j] = (short)h;
    lo[j] = (short)f2bf(f - bfh2f(h));
  }
  *(short8v*)&wh[dst] = hi;
  *(short8v*)&wl[dst] = lo;
}

// ---------------- MFMA linear, LDS-staged, one matrix per block ---------------------
// grid = nmat * NBLK blocks; w = blockIdx/NBLK selects matrix, blk = blockIdx%NBLK the
// 64-row tile. Block tile M=64 x N=128, K in two 64-halves. 4 waves (2x2), wave tile
// 32x64. A fp32 -> bf16 hi/lo split in registers -> LDS; W staged by pure 16B copies
// from the pre-swizzled image. 3 MFMA per group, fp32 accumulate. LDS 48 KB.
__global__ __launch_bounds__(256) void k_linm(const float* __restrict__ in,
    const unsigned short* __restrict__ wh_img, const unsigned short* __restrict__ wl_img,
    int wbase,
    const float* __restrict__ b0, const float* __restrict__ b1, const float* __restrict__ b2,
    unsigned short* __restrict__ o0, unsigned short* __restrict__ o1,
    float* __restrict__ o2, int nrows) {
  __shared__ unsigned short s_ah[64 * 64];   // 8 KB
  __shared__ unsigned short s_al[64 * 64];   // 8 KB
  __shared__ unsigned short s_wh[128 * 64];  // 16 KB
  __shared__ unsigned short s_wl[128 * 64];  // 16 KB
  const unsigned w = blockIdx.x / NBLK;      // matrix index within this launch
  const unsigned blk = blockIdx.x % NBLK;
  const int tid = threadIdx.x;
  const int lane = tid & 63;
  const int wv = tid >> 6;
  const int wr = wv >> 1, wc = wv & 1;
  const int m0 = wr * 32, n0 = wc * 64;
  const int rbase = blk * 64;
  const int g = lane >> 4;
  const int lr = lane & 15;

  f32x4 acc[2][4];
  #pragma unroll
  for (int mt = 0; mt < 2; ++mt)
    #pragma unroll
    for (int nt = 0; nt < 4; ++nt)
      acc[mt][nt] = (f32x4){0.f, 0.f, 0.f, 0.f};

  for (int kh = 0; kh < 2; ++kh) {
    if (kh) __syncthreads();   // previous compute done before restage
    // stage A half: 64 rows x 8 slots (hi/lo split of fp32 input)
    #pragma unroll
    for (int it = 0; it < 2; ++it) {
      int c = it * 256 + tid;
      int row = c >> 3, slot = c & 7;
      int rg = rbase + row;
      float f[8];
      if (rg < nrows) {
        float4 a0 = *(const float4*)&in[(size_t)rg * 128 + kh * 64 + slot * 8];
        float4 a1 = *(const float4*)&in[(size_t)rg * 128 + kh * 64 + slot * 8 + 4];
        f[0] = a0.x; f[1] = a0.y; f[2] = a0.z; f[3] = a0.w;
        f[4] = a1.x; f[5] = a1.y; f[6] = a1.z; f[7] = a1.w;
      } else {
        #pragma unroll
        for (int j = 0; j < 8; ++j) f[j] = 0.f;
      }
      short8v hi, lo;
      #pragma unroll
      for (int j = 0; j < 8; ++j) {
        unsigned short h = f2bf(f[j]);
        hi[j] = (short)h;
        lo[j] = (short)f2bf(f[j] - bfh2f(h));
      }
      int idx = row * 64 + 8 * (slot ^ (row & 7));
      *(short8v*)&s_ah[idx] = hi;
      *(short8v*)&s_al[idx] = lo;
    }
    // stage W half: pure 16B copies, image pre-swizzled
    {
      const unsigned short* sh = wh_img + (size_t)((wbase + w) * 2 + kh) * 8192;
      const unsigned short* sl = wl_img + (size_t)((wbase + w) * 2 + kh) * 8192;
      #pragma unroll
      for (int i = 0; i < 4; ++i) {
        int c = (i * 256 + tid) * 8;
        *(short8v*)&s_wh[c] = *(const short8v*)&sh[c];
        *(short8v*)&s_wl[c] = *(const short8v*)&sl[c];
      }
    }
    __syncthreads();
    #pragma unroll
    for (int ks = 0; ks < 2; ++ks) {
      short8v ah[2], al[2];
      #pragma unroll
      for (int mt = 0; mt < 2; ++mt) {
        int row = m0 + mt * 16 + lr;
        int idx = row * 64 + 8 * ((ks * 4 + g) ^ (row & 7));
        ah[mt] = *(const short8v*)&s_ah[idx];
        al[mt] = *(const short8v*)&s_al[idx];
      }
      #pragma unroll
      for (int nt = 0; nt < 4; ++nt) {
        int row = n0 + nt * 16 + lr;
        int idx = row * 64 + 8 * ((ks * 4 + g) ^ (row & 7));
        short8v bh = *(const short8v*)&s_wh[idx];
        short8v bl = *(const short8v*)&s_wl[idx];
        #pragma unroll
        for (int mt = 0; mt < 2; ++mt) {
          acc[mt][nt] = __builtin_amdgcn_mfma_f32_16x16x32_bf16(ah[mt], bh, acc[mt][nt], 0, 0, 0);
          acc[mt][nt] = __builtin_amdgcn_mfma_f32_16x16x32_bf16(ah[mt], bl, acc[mt][nt], 0, 0, 0);
          acc[mt][nt] = __builtin_amdgcn_mfma_f32_16x16x32_bf16(al[mt], bh, acc[mt][nt], 0, 0, 0);
        }
      }
    }
  }
  // epilogue: D row = 4*g + i, col = lr within each 16x16 tile
  const float* bp = (w == 0) ? b0 : (w == 1) ? b1 : b2;
  #pragma unroll
  for (int nt = 0; nt < 4; ++nt) {
    float bv = bp[n0 + nt * 16 + lr];
    #pragma unroll
    for (int mt = 0; mt < 2; ++mt)
      #pragma unroll
      for (int i = 0; i < 4; ++i) {
        int r = rbase + m0 + mt * 16 + 4 * g + i;
        if (r < nrows) {
          float vv = acc[mt][nt][i] + bv;
          size_t o = (size_t)r * 128 + n0 + nt * 16 + lr;
          if (w == 2) o2[o] = vv;
          else if (w == 1) o1[o] = f2bf(vv);
          else o0[o] = f2bf(vv);
        }
      }
  }
}

__device__ __forceinline__ float lrelu(float x) { return x > 0.f ? x : 0.2f * x; }

// ---------------- GATv2: bf16 gathers, no-max softmax (|s| <= ~2), 4-wide MLP ----
__global__ __launch_bounds__(256) void k_gat(const unsigned short* __restrict__ xl,
    const unsigned short* __restrict__ xr, const int* __restrict__ offs,
    const int* __restrict__ ssrc, const float* __restrict__ att,
    const float* __restrict__ bias, const float* __restrict__ resid,
    float* __restrict__ out) {
  int grp = threadIdx.x >> 5;
  int lane = threadIdx.x & 31;
  int n = blockIdx.x * 8 + grp;
  if (n >= NN) return;
  float4 att4 = ((const float4*)att)[lane];
  ushort4 xu = ((const ushort4*)xr)[(size_t)n * 32 + lane];
  float4 xr4 = make_float4(bfh2f(xu.x), bfh2f(xu.y), bfh2f(xu.z), bfh2f(xu.w));
  int e0 = offs[n], e1 = offs[n + 1];
  float den = 0.f;
  float4 acc = make_float4(0.f, 0.f, 0.f, 0.f);
  int e = e0;
  for (; e + 3 < e1; e += 4) {
    ushort4 u[4];
    #pragma unroll
    for (int j = 0; j < 4; ++j) {
      int s = ssrc[e + j];
      u[j] = ((const ushort4*)xl)[(size_t)s * 32 + lane];
    }
    #pragma unroll
    for (int j = 0; j < 4; ++j) {
      float4 v = make_float4(bfh2f(u[j].x), bfh2f(u[j].y), bfh2f(u[j].z), bfh2f(u[j].w));
      float p = lrelu(v.x + xr4.x) * att4.x + lrelu(v.y + xr4.y) * att4.y +
                lrelu(v.z + xr4.z) * att4.z + lrelu(v.w + xr4.w) * att4.w;
      p += __shfl_xor(p, 1, 64); p += __shfl_xor(p, 2, 64); p += __shfl_xor(p, 4, 64);
      float w = __expf(p);
      den += w;
      acc.x += w * v.x; acc.y += w * v.y; acc.z += w * v.z; acc.w += w * v.w;
    }
  }
  for (; e < e1; ++e) {
    int s = ssrc[e];
    ushort4 u0 = ((const ushort4*)xl)[(size_t)s * 32 + lane];
    float4 v = make_float4(bfh2f(u0.x), bfh2f(u0.y), bfh2f(u0.z), bfh2f(u0.w));
    float p = lrelu(v.x + xr4.x) * att4.x + lrelu(v.y + xr4.y) * att4.y +
              lrelu(v.z + xr4.z) * att4.z + lrelu(v.w + xr4.w) * att4.w;
    p += __shfl_xor(p, 1, 64); p += __shfl_xor(p, 2, 64); p += __shfl_xor(p, 4, 64);
    float w = __expf(p);
    den += w;
    acc.x += w * v.x; acc.y += w * v.y; acc.z += w * v.z; acc.w += w * v.w;
  }
  float inv = (den > 0.f) ? 1.f / den : 0.f;
  float4 b4 = ((const float4*)bias)[lane];
  float4 r4 = ((const float4*)resid)[(size_t)n * 32 + lane];
  float4 o;
  o.x = fmaxf(acc.x * inv + b4.x, 0.f) + r4.x;
  o.y = fmaxf(acc.y * inv + b4.y, 0.f) + r4.y;
  o.z = fmaxf(acc.z * inv + b4.z, 0.f) + r4.z;
  o.w = fmaxf(acc.w * inv + b4.w, 0.f) + r4.w;
  ((float4*)out)[(size_t)n * 32 + lane] = o;
}

// ---------------- mean-pool over sorted batch, run-length-compressed atomics ----------------
__global__ __launch_bounds__(256) void k_pool(const float* __restrict__ h,
    const int* __restrict__ batch, float* __restrict__ pooled) {
  int col = threadIdx.x & 127;
  int ro = threadIdx.x >> 7;
  int n0 = blockIdx.x * 128;
  float rs = 0.f;
  int cb = -1;
  for (int i = ro; i < 128; i += 2) {
    int n = n0 + i;
    if (n >= NN) break;
    int bb = batch[n];
    if (bb != cb) {
      if (cb >= 0) atomicAdd(&pooled[cb * FD + col], rs);
      rs = 0.f; cb = bb;
    }
    rs += h[(size_t)n * FD + col];
  }
  if (cb >= 0) atomicAdd(&pooled[cb * FD + col], rs);
}

// ---------------- MLP head: one block per graph ----------------
__global__ __launch_bounds__(128) void k_mlp(const float* __restrict__ pooled,
    const int* __restrict__ batch, const float* __restrict__ domain,
    const float* __restrict__ Wg, const float* __restrict__ bg,
    const float* __restrict__ Wd, const float* __restrict__ bd,
    const float* __restrict__ Wf1, const float* __restrict__ bf1,
    const float* __restrict__ Wf2, const float* __restrict__ bf2,
    const float* __restrict__ Wf3, const float* __restrict__ bf3,
    float* __restrict__ out) {
  __shared__ float z[192];
  __shared__ float z1[128];
  __shared__ float z2[64];
  __shared__ float pm[128];
  __shared__ int cnt;
  int b = blockIdx.x, t = threadIdx.x;
  if (t == 0) {
    int lo = 0, hi = NN;
    while (lo < hi) { int mid = (lo + hi) >> 1; if (batch[mid] < b) lo = mid + 1; else hi = mid; }
    int lb = lo; lo = 0; hi = NN;
    while (lo < hi) { int mid = (lo + hi) >> 1; if (batch[mid] < b + 1) lo = mid + 1; else hi = mid; }
    cnt = lo - lb;
  }
  __syncthreads();
  float invc = 1.f / fmaxf((float)cnt, 1.f);
  pm[t] = pooled[b * FD + t] * invc;
  __syncthreads();
  {
    float a = bg[t];
    for (int k = 0; k < 128; ++k) a += pm[k] * Wg[t * 128 + k];
    z[t] = fmaxf(a, 0.f);
  }
  if (t < 64) {
    float a = bd[t];
    for (int k = 0; k < 32; ++k) a += domain[b * 32 + k] * Wd[t * 32 + k];
    z[128 + t] = fmaxf(a, 0.f);
  }
  __syncthreads();
  {
    float a = bf1[t];
    for (int k = 0; k < 192; ++k) a += z[k] * Wf1[t * 192 + k];
    z1[t] = fmaxf(a, 0.f);
  }
  __syncthreads();
  if (t < 64) {
    float a = bf2[t];
    for (int k = 0; k < 128; ++k) a += z1[k] * Wf2[t * 128 + k];
    z2[t] = fmaxf(a, 0.f);
  }
  __syncthreads();
  if (t < 64) {
    float v = z2[t] * Wf3[t];
    for (int off = 1; off < 64; off <<= 1) v += __shfl_xor(v, off, 64);
    if (t == 0) out[b] = v + bf3[0];
  }
}

extern "C" void kernel_launch(void* const* d_in, const int* in_sizes, int n_in,
                              void* d_out, int out_size, void* d_ws, size_t ws_size,
                              hipStream_t stream) {
  const float* x      = (const float*)d_in[0];
  const float* domain = (const float*)d_in[1];
  const float* Wl1 = (const float*)d_in[2];  const float* bl1 = (const float*)d_in[3];
  const float* Wr1 = (const float*)d_in[4];  const float* br1 = (const float*)d_in[5];
  const float* att1= (const float*)d_in[6];  const float* bias1=(const float*)d_in[7];
  const float* Wl2 = (const float*)d_in[8];  const float* bl2 = (const float*)d_in[9];
  const float* Wr2 = (const float*)d_in[10]; const float* br2 = (const float*)d_in[11];
  const float* att2= (const float*)d_in[12]; const float* bias2=(const float*)d_in[13];
  const float* Wres= (const float*)d_in[14]; const float* bres= (const float*)d_in[15];
  const float* Wd  = (const float*)d_in[16]; const float* bd  = (const float*)d_in[17];
  const float* Wg  = (const float*)d_in[18]; const float* bg  = (const float*)d_in[19];
  const float* Wf1 = (const float*)d_in[20]; const float* bf1 = (const float*)d_in[21];
  const float* Wf2 = (const float*)d_in[22]; const float* bf2 = (const float*)d_in[23];
  const float* Wf3 = (const float*)d_in[24]; const float* bf3 = (const float*)d_in[25];
  const int* ei    = (const int*)d_in[26];
  const int* batch = (const int*)d_in[27];
  const int* esrc = ei;
  const int* edst = ei + NE;
  float* outp = (float*)d_out;

  char* p = (char*)d_ws;
  auto carve = [&](size_t bytes) { char* r = p; p += (bytes + 255) & ~(size_t)255; return r; };
  int* bcnt     = (int*)carve((size_t)NBUK * 4);
  int* bbase    = (int*)carve((size_t)(NBUK + 1) * 4);
  int* bcur     = (int*)carve((size_t)NBUK * 4);
  int* tmpv     = (int*)carve((size_t)NE * 4);
  int* ssrc     = (int*)carve((size_t)NE * 4);
  int* offs     = (int*)carve((size_t)(NN + 1) * 4);
  unsigned short* wh = (unsigned short*)carve((size_t)5 * 2 * 8192 * 2);
  unsigned short* wl = (unsigned short*)carve((size_t)5 * 2 * 8192 * 2);
  unsigned short* xl = (unsigned short*)carve((size_t)NN * FD * 2);
  unsigned short* xr = (unsigned short*)carve((size_t)NN * FD * 2);
  float* res    = (float*)carve((size_t)NN * FD * 4);
  float* h1     = (float*)carve((size_t)NN * FD * 4);
  float* pooled = (float*)carve((size_t)NB * FD * 4);
  float* h2 = res;   // res dead after first GAT; alias

  dim3 b256(256);
  hipLaunchKernelGGL(k_init, dim3((NB * FD + 255) / 256), b256, 0, stream, bcnt, pooled);
  hipLaunchKernelGGL(k_wprep, dim3(40), b256, 0, stream, Wl1, Wr1, Wres, Wl2, Wr2, wh, wl);
  hipLaunchKernelGGL(k_bhist, dim3(256), b256, 0, stream, edst, bcnt);
  hipLaunchKernelGGL(k_bscan, dim3(1), b256, 0, stream, bcnt, bbase, bcur);
  hipLaunchKernelGGL(k_bscatter, dim3(256), b256, 0, stream, esrc, edst, bcur, tmpv);
  hipLaunchKernelGGL(k_bcsr, dim3(NBUK), b256, 0, stream, tmpv, bbase, offs, ssrc);

  // layer 1: {xl, xr, res} in one launch (w = blockIdx / NBLK)
  hipLaunchKernelGGL(k_linm, dim3(3 * NBLK), b256, 0, stream,
                     x, wh, wl, 0, bl1, br1, bres, xl, xr, res, NN);
  hipLaunchKernelGGL(k_gat, dim3((NN + 7) / 8), b256, 0, stream, xl, xr, offs, ssrc, att1, bias1, res, h1);
  // layer 2: {xl, xr} in one launch
  hipLaunchKernelGGL(k_linm, dim3(2 * NBLK), b256, 0, stream,
                     h1, wh, wl, 3, bl2, br2, (const float*)nullptr, xl, xr, (float*)nullptr, NN);
  hipLaunchKernelGGL(k_gat, dim3((NN + 7) / 8), b256, 0, stream, xl, xr, offs, ssrc, att2, bias2, h1, h2);
  hipLaunchKernelGGL(k_pool, dim3((NN + 127) / 128), b256, 0, stream, h2, batch, pooled);
  hipLaunchKernelGGL(k_mlp, dim3(NB), dim3(128), 0, stream, pooled, batch, domain,
                     Wg, bg, Wd, bd, Wf1, bf1, Wf2, bf2, Wf3, bf3, outp);
}